// Round 9
// baseline (5235.837 us; speedup 1.0000x reference)
//
#include <hip/hip_runtime.h>
#include <hip/hip_bf16.h>

#define Bb 32
#define Tt 512
#define Ii 256
#define Hh 512
#define Oo 128
#define NWG 32   // total wgs in recurrence (each handles BOTH directions)

using bf16x8 = __attribute__((ext_vector_type(8))) __bf16;
using f32x4  = __attribute__((ext_vector_type(4))) float;

__device__ __forceinline__ bf16x8 f32x8_to_bf16(const float* p) {
    const float4 u = *reinterpret_cast<const float4*>(p);
    const float4 v = *reinterpret_cast<const float4*>(p + 4);
    bf16x8 r;
    r[0] = (__bf16)u.x; r[1] = (__bf16)u.y; r[2] = (__bf16)u.z; r[3] = (__bf16)u.w;
    r[4] = (__bf16)v.x; r[5] = (__bf16)v.y; r[6] = (__bf16)v.z; r[7] = (__bf16)v.w;
    return r;
}

__device__ __forceinline__ float sigm(float x) { return 1.f / (1.f + __expf(-x)); }
__device__ __forceinline__ float tanh_fast(float x) {
    const float e = __expf(2.f * x);
    return 1.f - 2.f / (e + 1.f);
}
__device__ __forceinline__ unsigned short bfbits(float x) {
    return __builtin_bit_cast(unsigned short, (__bf16)x);
}
__device__ __forceinline__ float us2f(unsigned short u) {
    return __builtin_bit_cast(float, (unsigned)u << 16);
}

// ---------------- setup: zero flags, build initial h (fwd=0, bwd=bh0) -------
__global__ void k_setup(const float* __restrict__ bh0,
                        __bf16* __restrict__ hinit, int* __restrict__ flags) {
    const int tid = blockIdx.x * 256 + threadIdx.x;
    if (tid < 64) flags[tid] = 0;          // 256 bytes of u8 flags
    if (tid < Bb * Hh) {
        hinit[tid] = (__bf16)0.f;
        hinit[Bb * Hh + tid] = (__bf16)bh0[tid & (Hh - 1)];
    }
}

// ---------------- one-time Wh f32 -> bf16, layout [4][512 hcol][512 k] -------
__global__ __launch_bounds__(256) void k_wcvt(
    const float* __restrict__ Wf, const float* __restrict__ Wi,
    const float* __restrict__ Wo, const float* __restrict__ Wc,
    __bf16* __restrict__ Whb)
{
    const int e = (blockIdx.x * 256 + threadIdx.x) * 4;
    const int g = e >> 18;
    const int rem = e & 262143;
    const int hr = rem >> 9;
    const int k  = rem & 511;
    const float* W = (g == 0) ? Wf : (g == 1) ? Wi : (g == 2) ? Wo : Wc;
    const float4 v = *reinterpret_cast<const float4*>(W + (long)hr * 768 + Ii + k);
    uint2 pk;
    pk.x = ((unsigned)bfbits(v.y) << 16) | bfbits(v.x);
    pk.y = ((unsigned)bfbits(v.w) << 16) | bfbits(v.z);
    *reinterpret_cast<uint2*>(Whb + e) = pk;
}

// ---------------- xproj = x @ Wx^T + b  -> [T][4H][B] bf16 -------------------
__global__ __launch_bounds__(256) void k_xproj(
    const float* __restrict__ x,
    const float* __restrict__ Wf, const float* __restrict__ bf_,
    const float* __restrict__ Wi, const float* __restrict__ bi_,
    const float* __restrict__ Wo, const float* __restrict__ bo_,
    const float* __restrict__ Wc, const float* __restrict__ bc_,
    __bf16* __restrict__ xproj)
{
    const int wgM = blockIdx.x;           // 0..255  (64 rows each)
    const int wgN = blockIdx.y;           // 0..15   (128 cols each)
    const int tid = threadIdx.x;
    const int wave = tid >> 6, lane = tid & 63;
    const int mw = wave >> 1, nw = wave & 1;
    const int l15 = lane & 15, lhi = lane >> 4;

    const int gamma = wgN >> 2;
    const float* W    = (gamma == 0) ? Wf : (gamma == 1) ? Wi : (gamma == 2) ? Wo : Wc;
    const float* bptr = (gamma == 0) ? bf_ : (gamma == 1) ? bi_ : (gamma == 2) ? bo_ : bc_;

    f32x4 acc[2][4];
#pragma unroll
    for (int m = 0; m < 2; m++)
#pragma unroll
        for (int n = 0; n < 4; n++) acc[m][n] = f32x4{0.f, 0.f, 0.f, 0.f};

    const int rowbase = wgM * 64 + mw * 32;
    const int colbase = wgN * 128 + nw * 64;

#pragma unroll
    for (int kk = 0; kk < 8; ++kk) {
        const int k0 = kk * 32 + lhi * 8;
        bf16x8 a[2], b[4];
#pragma unroll
        for (int m = 0; m < 2; m++) {
            const int r = rowbase + m * 16 + l15;        // x row = b*T + t
            a[m] = f32x8_to_bf16(x + (long)r * Ii + k0);
        }
#pragma unroll
        for (int n = 0; n < 4; n++) {
            const int g = colbase + n * 16 + l15;
            b[n] = f32x8_to_bf16(W + (long)(g & 511) * 768 + k0);
        }
#pragma unroll
        for (int m = 0; m < 2; m++)
#pragma unroll
            for (int n = 0; n < 4; n++)
                acc[m][n] = __builtin_amdgcn_mfma_f32_16x16x32_bf16(a[m], b[n], acc[m][n], 0, 0, 0);
    }

#pragma unroll
    for (int m = 0; m < 2; m++)
#pragma unroll
        for (int n = 0; n < 4; n++) {
            const int g = colbase + n * 16 + l15;        // global gate-col 0..2047
            const float bias = bptr[g & 511];
#pragma unroll
            for (int r = 0; r < 4; r++) {
                const int R = rowbase + m * 16 + lhi * 4 + r;   // = b*T + t
                const int t = R & (Tt - 1), bb = R >> 9;
                xproj[((long)t * 2048 + g) * Bb + bb] = (__bf16)(acc[m][n][r] + bias);
            }
        }
}

// ---------------- recurrence: 32 wgs, BOTH dirs per wg, W in LDS -------------
__global__ __launch_bounds__(256, 1) void k_rec(
    const __bf16* __restrict__ Whb,    // [4][512][512] bf16
    const float* __restrict__ bc0,
    const __bf16* __restrict__ xproj,  // [T][4H][B]
    __bf16* __restrict__ hs,           // [2][T][B][H]
    const __bf16* __restrict__ hinit,  // [2][B][H]
    unsigned char* flags)              // [128 producers][2 dirs] u8
{
    const int gsel = blockIdx.x;            // owns h-cols [gsel*16, +16), both dirs
    const int tid  = threadIdx.x;
    const int wave = tid >> 6;              // 0..3 : 4 h-cols each
    const int lane = tid & 63;
    const int l15  = lane & 15, lhi = lane >> 4;

    __shared__ __bf16 Wlds[64 * 512];       // 64 KiB, rows j = hc_local*4+gate
    __shared__ __bf16 hb[2][Bb * Hh];       // dir f / dir b, 32 KiB each

    // one-time: copy this wg's weight slice into LDS (swizzled)
    char* wl = reinterpret_cast<char*>(Wlds);
    for (int c = tid; c < 4096; c += 256) {
        const int row = c >> 6, q = c & 63;
        const int gate = row & 3;
        const int hc   = gsel * 16 + (row >> 4) * 4 + ((row & 15) >> 2);
        const bf16x8 w = *reinterpret_cast<const bf16x8*>(
            Whb + (long)(gate * 512 + hc) * 512 + q * 8);
        *reinterpret_cast<bf16x8*>(wl + row * 1024 + ((q * 16) ^ ((row & 7) << 4))) = w;
    }

    const int hcol = gsel * 16 + wave * 4 + lhi;
    float cf0 = 0.f, cf1 = 0.f;                       // fwd cell, batches l15 / 16+l15
    float cb0 = bc0[hcol], cb1 = cb0;                 // bwd cell

    __bf16* hs_f = hs;
    __bf16* hs_b = hs + (long)Tt * Bb * Hh;

    const char* wbase = wl + (wave * 16 + l15) * 1024;
    const int asw = (l15 & 7) << 4;
    const int bsw = (l15 & 7) << 4;
    const int srow = tid >> 6;
    const int sck  = tid & 63;
    const int prod = gsel * 4 + wave;                 // producer id 0..127

    for (int s = 0; s < Tt; ++s) {
        const int tf = s, tb = Tt - 1 - s;

        // coalesced xproj prefetch, both dirs (layout [T][4H][B])
        unsigned short xf0[4], xf1[4], xb0[4], xb1[4];
#pragma unroll
        for (int g = 0; g < 4; ++g) {
            const __bf16* pf = xproj + ((long)tf * 2048 + g * 512 + hcol) * Bb;
            const __bf16* pb = xproj + ((long)tb * 2048 + g * 512 + hcol) * Bb;
            xf0[g] = __builtin_bit_cast(unsigned short, pf[l15]);
            xf1[g] = __builtin_bit_cast(unsigned short, pf[16 + l15]);
            xb0[g] = __builtin_bit_cast(unsigned short, pb[l15]);
            xb1[g] = __builtin_bit_cast(unsigned short, pb[16 + l15]);
        }

        // single-dword poll: lane covers producers 2*lane, 2*lane+1, both dirs
        if (s > 0) {
            const unsigned es = (unsigned)(s & 255);
            for (int p = 0; p < 8192; ++p) {
                const unsigned v = __hip_atomic_load(
                    reinterpret_cast<const unsigned*>(flags) + lane,
                    __ATOMIC_RELAXED, __HIP_MEMORY_SCOPE_AGENT);
                const bool ok =
                    ((unsigned char)((v & 255) - es) <= 1) &&
                    ((unsigned char)(((v >> 8) & 255) - es) <= 1) &&
                    ((unsigned char)(((v >> 16) & 255) - es) <= 1) &&
                    ((unsigned char)(((v >> 24) & 255) - es) <= 1);
                if (__all(ok)) break;
                __builtin_amdgcn_s_sleep(1);
            }
        }

        // stage h_{s-1} for both dirs (coherent loads, 16B XOR swizzle)
        const __bf16* hpf = (s == 0) ? hinit : (hs_f + (long)(tf - 1) * Bb * Hh);
        const __bf16* hpb = (s == 0) ? (hinit + Bb * Hh) : (hs_b + (long)(tb + 1) * Bb * Hh);
        const char* gf = reinterpret_cast<const char*>(hpf) + srow * 1024 + sck * 16;
        const char* gb = reinterpret_cast<const char*>(hpb) + srow * 1024 + sck * 16;
        f32x4 f0, f1, f2, f3, f4, f5, f6, f7;
        f32x4 b0_, b1_, b2_, b3_, b4_, b5_, b6_, b7_;
#define LDC(ptr, i, dst) asm volatile("global_load_dwordx4 %0, %1, off sc0 sc1" \
                                      : "=&v"(dst) : "v"(ptr + (i) * 4096) : "memory")
        LDC(gf, 0, f0); LDC(gf, 1, f1); LDC(gf, 2, f2); LDC(gf, 3, f3);
        LDC(gf, 4, f4); LDC(gf, 5, f5); LDC(gf, 6, f6); LDC(gf, 7, f7);
        LDC(gb, 0, b0_); LDC(gb, 1, b1_); LDC(gb, 2, b2_); LDC(gb, 3, b3_);
        LDC(gb, 4, b4_); LDC(gb, 5, b5_); LDC(gb, 6, b6_); LDC(gb, 7, b7_);
#undef LDC
        asm volatile("s_waitcnt vmcnt(0)" ::: "memory");
        __builtin_amdgcn_sched_barrier(0);
        char* hcf = reinterpret_cast<char*>(hb[0]);
        char* hcb = reinterpret_cast<char*>(hb[1]);
#define STC(base, i, src) { const int r = srow + 4 * (i); \
        *reinterpret_cast<f32x4*>(base + r * 1024 + ((sck * 16) ^ ((r & 7) << 4))) = src; }
        STC(hcf, 0, f0); STC(hcf, 1, f1); STC(hcf, 2, f2); STC(hcf, 3, f3);
        STC(hcf, 4, f4); STC(hcf, 5, f5); STC(hcf, 6, f6); STC(hcf, 7, f7);
        STC(hcb, 0, b0_); STC(hcb, 1, b1_); STC(hcb, 2, b2_); STC(hcb, 3, b3_);
        STC(hcb, 4, b4_); STC(hcb, 5, b5_); STC(hcb, 6, b6_); STC(hcb, 7, b7_);
#undef STC
        __syncthreads();    // the only barrier per iteration

        // ---- forward GEMM: C[j][b] = sum_k W[j][k] * hf[b][k] ----
        f32x4 af0 = f32x4{0.f, 0.f, 0.f, 0.f};
        f32x4 af1 = f32x4{0.f, 0.f, 0.f, 0.f};
#pragma unroll
        for (int kk = 0; kk < 16; ++kk) {
            const int kb = kk * 64 + lhi * 16;
            const bf16x8 wv = *reinterpret_cast<const bf16x8*>(wbase + (kb ^ asw));
            const bf16x8 h0 = *reinterpret_cast<const bf16x8*>(hcf + l15 * 1024 + (kb ^ bsw));
            const bf16x8 h1 = *reinterpret_cast<const bf16x8*>(hcf + (16 + l15) * 1024 + (kb ^ bsw));
            af0 = __builtin_amdgcn_mfma_f32_16x16x32_bf16(wv, h0, af0, 0, 0, 0);
            af1 = __builtin_amdgcn_mfma_f32_16x16x32_bf16(wv, h1, af1, 0, 0, 0);
        }
        // fwd cell + store (no drain yet — hidden under bwd GEMM)
        float hv0, hv1;
        {
            const float gfv = us2f(xf0[0]) + af0[0];
            const float giv = us2f(xf0[1]) + af0[1];
            const float gov = us2f(xf0[2]) + af0[2];
            const float gcv = us2f(xf0[3]) + af0[3];
            cf0 = sigm(gfv) * cf0 + sigm(giv) * tanh_fast(gcv);
            hv0 = sigm(gov) * tanh_fast(cf0);
        }
        {
            const float gfv = us2f(xf1[0]) + af1[0];
            const float giv = us2f(xf1[1]) + af1[1];
            const float gov = us2f(xf1[2]) + af1[2];
            const float gcv = us2f(xf1[3]) + af1[3];
            cf1 = sigm(gfv) * cf1 + sigm(giv) * tanh_fast(gcv);
            hv1 = sigm(gov) * tanh_fast(cf1);
        }
        {
            const unsigned u0 = bfbits(hv0), u1 = bfbits(hv1);
            char* d0 = reinterpret_cast<char*>(hs_f + ((long)tf * Bb + l15) * Hh + hcol);
            char* d1 = reinterpret_cast<char*>(hs_f + ((long)tf * Bb + 16 + l15) * Hh + hcol);
            asm volatile("global_store_short %0, %1, off sc0 sc1" :: "v"(d0), "v"(u0) : "memory");
            asm volatile("global_store_short %0, %1, off sc0 sc1" :: "v"(d1), "v"(u1) : "memory");
        }

        // ---- backward GEMM (hides fwd store drain) ----
        f32x4 ab0 = f32x4{0.f, 0.f, 0.f, 0.f};
        f32x4 ab1 = f32x4{0.f, 0.f, 0.f, 0.f};
#pragma unroll
        for (int kk = 0; kk < 16; ++kk) {
            const int kb = kk * 64 + lhi * 16;
            const bf16x8 wv = *reinterpret_cast<const bf16x8*>(wbase + (kb ^ asw));
            const bf16x8 h0 = *reinterpret_cast<const bf16x8*>(hcb + l15 * 1024 + (kb ^ bsw));
            const bf16x8 h1 = *reinterpret_cast<const bf16x8*>(hcb + (16 + l15) * 1024 + (kb ^ bsw));
            ab0 = __builtin_amdgcn_mfma_f32_16x16x32_bf16(wv, h0, ab0, 0, 0, 0);
            ab1 = __builtin_amdgcn_mfma_f32_16x16x32_bf16(wv, h1, ab1, 0, 0, 0);
        }
        // fwd h now drained at LLC -> publish fwd flag
        asm volatile("s_waitcnt vmcnt(0)" ::: "memory");
        if (lane == 0) {
            const unsigned fv = (unsigned)((s + 1) & 255);
            char* fp = reinterpret_cast<char*>(flags) + prod * 2;
            asm volatile("global_store_byte %0, %1, off sc0 sc1" :: "v"(fp), "v"(fv) : "memory");
        }
        // bwd cell + store + drain + flag
        {
            const float gfv = us2f(xb0[0]) + ab0[0];
            const float giv = us2f(xb0[1]) + ab0[1];
            const float gov = us2f(xb0[2]) + ab0[2];
            const float gcv = us2f(xb0[3]) + ab0[3];
            cb0 = sigm(gfv) * cb0 + sigm(giv) * tanh_fast(gcv);
            hv0 = sigm(gov) * tanh_fast(cb0);
        }
        {
            const float gfv = us2f(xb1[0]) + ab1[0];
            const float giv = us2f(xb1[1]) + ab1[1];
            const float gov = us2f(xb1[2]) + ab1[2];
            const float gcv = us2f(xb1[3]) + ab1[3];
            cb1 = sigm(gfv) * cb1 + sigm(giv) * tanh_fast(gcv);
            hv1 = sigm(gov) * tanh_fast(cb1);
        }
        {
            const unsigned u0 = bfbits(hv0), u1 = bfbits(hv1);
            char* d0 = reinterpret_cast<char*>(hs_b + ((long)tb * Bb + l15) * Hh + hcol);
            char* d1 = reinterpret_cast<char*>(hs_b + ((long)tb * Bb + 16 + l15) * Hh + hcol);
            asm volatile("global_store_short %0, %1, off sc0 sc1" :: "v"(d0), "v"(u0) : "memory");
            asm volatile("global_store_short %0, %1, off sc0 sc1" :: "v"(d1), "v"(u1) : "memory");
        }
        asm volatile("s_waitcnt vmcnt(0)" ::: "memory");
        if (lane == 0) {
            const unsigned fv = (unsigned)((s + 1) & 255);
            char* fp = reinterpret_cast<char*>(flags) + prod * 2 + 1;
            asm volatile("global_store_byte %0, %1, off sc0 sc1" :: "v"(fp), "v"(fv) : "memory");
        }
    }
}

// ---------------- out = cat(hf,hb) @ out_w^T + out_b -> [B][T][O] fp32 -------
__global__ __launch_bounds__(256) void k_out(
    const __bf16* __restrict__ hs,
    const float* __restrict__ out_w,
    const float* __restrict__ out_b,
    float* __restrict__ out)
{
    const int wgM = blockIdx.x;            // 0..255 (64 hs-rows each)
    const int tid = threadIdx.x;
    const int wave = tid >> 6, lane = tid & 63;
    const int mw = wave >> 1, nw = wave & 1;
    const int l15 = lane & 15, lhi = lane >> 4;

    f32x4 acc[2][4];
#pragma unroll
    for (int m = 0; m < 2; m++)
#pragma unroll
        for (int n = 0; n < 4; n++) acc[m][n] = f32x4{0.f, 0.f, 0.f, 0.f};

    const int rowbase = wgM * 64 + mw * 32;   // hs row = t*B + b
    const int colbase = nw * 64;

#pragma unroll 4
    for (int kk = 0; kk < 32; ++kk) {
        const int k0 = kk * 32 + lhi * 8;     // 0..1023
        const int d = k0 >> 9, hk = k0 & 511;
        bf16x8 a[2], b[4];
#pragma unroll
        for (int m = 0; m < 2; m++) {
            const int R = rowbase + m * 16 + l15;
            a[m] = *reinterpret_cast<const bf16x8*>(hs + ((long)d * 16384 + R) * 512 + hk);
        }
#pragma unroll
        for (int n = 0; n < 4; n++) {
            const int o = colbase + n * 16 + l15;
            b[n] = f32x8_to_bf16(out_w + (long)o * 1024 + k0);
        }
#pragma unroll
        for (int m = 0; m < 2; m++)
#pragma unroll
            for (int n = 0; n < 4; n++)
                acc[m][n] = __builtin_amdgcn_mfma_f32_16x16x32_bf16(a[m], b[n], acc[m][n], 0, 0, 0);
    }

#pragma unroll
    for (int m = 0; m < 2; m++)
#pragma unroll
        for (int n = 0; n < 4; n++) {
            const int o = colbase + n * 16 + l15;
            const float bias = out_b[o];
#pragma unroll
            for (int r = 0; r < 4; r++) {
                const int R = rowbase + m * 16 + lhi * 4 + r;   // t*32 + b
                const int tt = R >> 5, bb = R & 31;
                out[((long)bb * Tt + tt) * Oo + o] = acc[m][n][r] + bias;
            }
        }
}

// ---------------- launcher ---------------------------------------------------
extern "C" void kernel_launch(void* const* d_in, const int* in_sizes, int n_in,
                              void* d_out, int out_size, void* d_ws, size_t ws_size,
                              hipStream_t stream) {
    (void)in_sizes; (void)n_in; (void)out_size; (void)ws_size;
    const float* x    = (const float*)d_in[0];
    const float* Wf_w = (const float*)d_in[1];
    const float* Wf_b = (const float*)d_in[2];
    const float* Wi_w = (const float*)d_in[3];
    const float* Wi_b = (const float*)d_in[4];
    const float* Wo_w = (const float*)d_in[5];
    const float* Wo_b = (const float*)d_in[6];
    const float* Wc_w = (const float*)d_in[7];
    const float* Wc_b = (const float*)d_in[8];
    const float* out_w = (const float*)d_in[9];
    const float* out_b = (const float*)d_in[10];
    const float* bh0  = (const float*)d_in[11];
    const float* bc0  = (const float*)d_in[12];

    char* ws = (char*)d_ws;
    __bf16* xproj = (__bf16*)(ws);                       // 67108864 B  [T][4H][B]
    __bf16* hs    = (__bf16*)(ws + 67108864);            // 33554432 B
    __bf16* hinit = (__bf16*)(ws + 100663296);           // 65536 B
    __bf16* Whb   = (__bf16*)(ws + 100728832);           // 2097152 B
    unsigned char* flags = (unsigned char*)(ws + 102825984);  // 256 B

    k_setup<<<64, 256, 0, stream>>>(bh0, hinit, (int*)flags);
    k_wcvt<<<1024, 256, 0, stream>>>(Wf_w, Wi_w, Wo_w, Wc_w, Whb);
    dim3 g1(256, 16);
    k_xproj<<<g1, 256, 0, stream>>>(x, Wf_w, Wf_b, Wi_w, Wi_b, Wo_w, Wo_b, Wc_w, Wc_b, xproj);
    k_rec<<<NWG, 256, 0, stream>>>(Whb, bc0, xproj, hs, hinit, flags);
    k_out<<<256, 256, 0, stream>>>(hs, out_w, out_b, (float*)d_out);
}